// Round 11
// baseline (6691.780 us; speedup 1.0000x reference)
//
#include <hip/hip_runtime.h>

#define N 128
#define PAD2 129
#define NL 8128
#define POWER_IT 12   // even: last iteration ends with CholQR (orthonormal for Ritz)
#define INV_IT 5
#define NTHREADS 1024

// LDS layout (doubles first):
//   Ad[128*129] fp64 matrix (132096 B) -> L,U after LU
//   dinvd[128]  1/U[k,k]
//   dmisc[24]   [0]=lmax, [1..16]=lmin per wave
//   dred[24]    reduction scratch (norm: 8, CholQR/Gram: 20)
//   dG[16]      4x4 R^{-1} (upper) -- computed by tid0, read by 128 threads (spill fix r11)
// then float4 region (padded index XI): fX4[143], fW4[143]
#define NDBL (16512 + 128 + 24 + 24 + 16)     // 16704 doubles = 133632 B
#define SMEM_BYTES (NDBL * 8 + 2 * 143 * 16)  // 133632 + 4576 = 138208
#define XI(j) ((j) + ((j) >> 3))              // bank-skew pad for float4 vectors

static __device__ __forceinline__ float hashf(unsigned x) {
    x ^= 2747636419u; x *= 2654435769u; x ^= x >> 16;
    x *= 2654435769u; x ^= x >> 16; x *= 2654435769u;
    return ((float)(x >> 8)) * (1.0f / 16777216.0f) - 0.5f;
}
static __device__ __forceinline__ double readlane_d(double x, int lane) {
    int lo = __builtin_amdgcn_readlane(__double2loint(x), lane);
    int hi = __builtin_amdgcn_readlane(__double2hiint(x), lane);
    return __hiloint2double(hi, lo);
}

// Cholesky of 4x4 Gram (packed upper, 10) -> C = R^{-1} (upper, row-major 4x4).
// Called by tid0 ONLY (exec-masked scratch ok); C may point to LDS.
static __device__ __forceinline__ void cholInvC(const double* Gp, double* C) {
    double g[4][4];
    int c = 0;
    #pragma unroll
    for (int a = 0; a < 4; ++a)
        #pragma unroll
        for (int b2 = a; b2 < 4; ++b2) { g[a][b2] = Gp[c]; g[b2][a] = Gp[c]; ++c; }
    double R[4][4];
    #pragma unroll
    for (int i = 0; i < 4; ++i) {
        double d = g[i][i];
        #pragma unroll
        for (int m = 0; m < 4; ++m) if (m < i) d -= R[m][i] * R[m][i];
        d = sqrt(fmax(d, 1e-300));
        R[i][i] = d;
        #pragma unroll
        for (int j = 0; j < 4; ++j) if (j > i) {
            double v = g[i][j];
            #pragma unroll
            for (int m = 0; m < 4; ++m) if (m < i) v -= R[m][i] * R[m][j];
            R[i][j] = v / d;
        }
    }
    #pragma unroll
    for (int j = 3; j >= 0; --j) {
        C[j*4 + j] = 1.0 / R[j][j];
        #pragma unroll
        for (int i = 3; i >= 0; --i) if (i < j) {
            double v = 0.0;
            #pragma unroll
            for (int m = 0; m < 4; ++m) if (m > i && m <= j) v += R[i][m] * C[m*4 + j];
            C[i*4 + j] = -v / R[i][i];
        }
        #pragma unroll
        for (int i = 0; i < 4; ++i) if (i > j) C[i*4 + j] = 0.0;
    }
}

static __device__ __forceinline__ double jacobi4_lmax(const double* Gp) {
    double g[4][4];
    int c = 0;
    #pragma unroll
    for (int a = 0; a < 4; ++a)
        #pragma unroll
        for (int b2 = a; b2 < 4; ++b2) { g[a][b2] = Gp[c]; g[b2][a] = Gp[c]; ++c; }
    #pragma unroll
    for (int sweep = 0; sweep < 6; ++sweep) {
        #pragma unroll
        for (int p = 0; p < 3; ++p) {
            #pragma unroll
            for (int q = p + 1; q < 4; ++q) {
                double apq = g[p][q];
                double tau = (g[q][q] - g[p][p]) / (2.0 * apq);
                double t = (tau >= 0.0 ? 1.0 : -1.0) / (fabs(tau) + sqrt(1.0 + tau * tau));
                if (fabs(apq) < 1e-280) t = 0.0;
                double cc = 1.0 / sqrt(1.0 + t * t);
                double ss = t * cc;
                #pragma unroll
                for (int r = 0; r < 4; ++r) {
                    double grp = g[r][p], grq = g[r][q];
                    g[r][p] = cc * grp - ss * grq;
                    g[r][q] = ss * grp + cc * grq;
                }
                #pragma unroll
                for (int r = 0; r < 4; ++r) {
                    double gpr = g[p][r], gqr = g[q][r];
                    g[p][r] = cc * gpr - ss * gqr;
                    g[q][r] = ss * gpr + cc * gqr;
                }
            }
        }
    }
    return fmax(fmax(g[0][0], g[1][1]), fmax(g[2][2], g[3][3]));
}

static __device__ __forceinline__ void cholqr2_d(double ya[2], double yb[2]) {
    double g00 = ya[0]*ya[0] + yb[0]*yb[0];
    double g01 = ya[0]*ya[1] + yb[0]*yb[1];
    double g11 = ya[1]*ya[1] + yb[1]*yb[1];
    #pragma unroll
    for (int o = 32; o > 0; o >>= 1) {
        g00 += __shfl_xor(g00, o);
        g01 += __shfl_xor(g01, o);
        g11 += __shfl_xor(g11, o);
    }
    double r00 = sqrt(fmax(g00, 1e-300));
    double r01 = g01 / r00;
    double r11 = sqrt(fmax(g11 - r01 * r01, fabs(g11) * 1e-26 + 1e-300));
    double c00 = 1.0 / r00, c11 = 1.0 / r11;
    double c01 = -r01 * c00 * c11;
    double a0 = ya[0]*c00,             b0 = yb[0]*c00;
    double a1 = ya[0]*c01 + ya[1]*c11, b1 = yb[0]*c01 + yb[1]*c11;
    ya[0] = a0; yb[0] = b0; ya[1] = a1; yb[1] = b1;
}

// One triangular sweep of the block-4 power iteration, all 16 waves.
// Row pr = tid>>3 (0..127); lane pc = tid&7 handles elements j = pc + 8t.
// Direct LDS reads: NO per-thread arrays (rule #20 / round-4+5 spill lesson).
// MODE 0: out = U  * in            (row, j >= pr)
// MODE 1: out = L  * in, unit diag (row, j <  pr, + in[pr])
// MODE 2: out = L^T* in, unit diag (col, j >  pr, + in[pr])
// MODE 3: out = U^T* in            (col, j <= pr)
template<int MODE>
static __device__ __forceinline__ void sweep4(const double* __restrict__ Ad,
                                              const float4* __restrict__ Xin,
                                              float4* __restrict__ Xout,
                                              int pr, int pc) {
    float a0 = 0.f, a1 = 0.f, a2 = 0.f, a3 = 0.f;
    #pragma unroll
    for (int t = 0; t < 16; ++t) {
        int j = pc + (t << 3);
        float a = (MODE < 2) ? (float)Ad[pr * PAD2 + j] : (float)Ad[j * PAD2 + pr];
        bool keep = (MODE == 0) ? (j >= pr) : (MODE == 1) ? (j < pr)
                  : (MODE == 2) ? (j > pr)  : (j <= pr);
        a = keep ? a : 0.f;
        float4 xv = Xin[XI(j)];
        a0 += a * xv.x; a1 += a * xv.y; a2 += a * xv.z; a3 += a * xv.w;
    }
    a0 += __shfl_xor(a0, 1); a0 += __shfl_xor(a0, 2); a0 += __shfl_xor(a0, 4);
    a1 += __shfl_xor(a1, 1); a1 += __shfl_xor(a1, 2); a1 += __shfl_xor(a1, 4);
    a2 += __shfl_xor(a2, 1); a2 += __shfl_xor(a2, 2); a2 += __shfl_xor(a2, 4);
    a3 += __shfl_xor(a3, 1); a3 += __shfl_xor(a3, 2); a3 += __shfl_xor(a3, 4);
    if (pc == 0) {
        float4 o = make_float4(a0, a1, a2, a3);
        if (MODE == 1 || MODE == 2) {
            float4 iv = Xin[XI(pr)];
            o.x += iv.x; o.y += iv.y; o.z += iv.z; o.w += iv.w;
        }
        Xout[XI(pr)] = o;
    }
}

__global__ __launch_bounds__(NTHREADS)
__attribute__((amdgpu_waves_per_eu(4, 4)))
void cond_kernel(const float* __restrict__ DD, const float* __restrict__ LE,
                 const float* __restrict__ SCL, double* __restrict__ conds)
{
    extern __shared__ char smraw[];
    double* Ad    = (double*)smraw;        // 16512
    double* dinvd = Ad + N * PAD2;         // 128
    double* dmisc = dinvd + 128;           // 24
    double* dred  = dmisc + 24;            // 24
    double* dG    = dred + 24;             // 16
    float4* fX4   = (float4*)(Ad + NDBL);  // 143
    float4* fW4   = fX4 + 143;             // 143

    const int tid = threadIdx.x;
    const int b   = blockIdx.x;
    const int wid = tid >> 6;
    const int l   = tid & 63;
    const int rB  = l + 64;
    const double s = (double)SCL[0];
    const float* dd = DD + (size_t)b * (N * N);
    const float* le = LE + (size_t)b * NL;

    // ---- stage DD -> fp64
    for (int t = tid; t < (N * N) / 4; t += NTHREADS) {
        float4 dv = reinterpret_cast<const float4*>(dd)[t];
        int elem = t * 4;
        int i = elem >> 7, j = elem & 127;
        double* dst = &Ad[i * PAD2 + j];
        dst[0] = (double)dv.x; dst[1] = (double)dv.y;
        dst[2] = (double)dv.z; dst[3] = (double)dv.w;
    }
    __syncthreads();

    const int pr_ = tid >> 5;   // 0..31: row in 32-row block
    const int pc_ = tid & 31;   // col group: cols pc_+32e, e<4

    // ---- Pass A: T = D + s * E^T D (E = strict-lower le), ascending 32-row blocks
    for (int KB = 0; KB < N; KB += 32) {
        const int k = KB + pr_;
        double acc[4];
        #pragma unroll
        for (int e = 0; e < 4; ++e) acc[e] = 0.0;
        int off = (KB + 1) * KB / 2 + k;
        #pragma unroll 4
        for (int i = KB + 1; i < N; ++i) {
            int offs = (i > k) ? off : 0;
            float lef = le[offs];
            double lv = (i > k) ? (double)lef : 0.0;
            #pragma unroll
            for (int e = 0; e < 4; ++e) acc[e] += lv * Ad[i * PAD2 + pc_ + 32 * e];
            off += i;
        }
        __syncthreads();
        #pragma unroll
        for (int e = 0; e < 4; ++e) Ad[k * PAD2 + pc_ + 32 * e] += s * acc[e];
        __syncthreads();
    }

    // ---- Pass B: P = T + s * E T, descending 32-row blocks
    for (int IB = N - 32; IB >= 0; IB -= 32) {
        const int i = IB + pr_;
        const float* er = le + i * (i - 1) / 2;
        double acc[4];
        #pragma unroll
        for (int e = 0; e < 4; ++e) acc[e] = 0.0;
        #pragma unroll 4
        for (int m = 0; m < IB + 32; ++m) {
            int mm = (m < i) ? m : 0;
            float lef = er[mm];
            double lv = (m < i) ? (double)lef : 0.0;
            #pragma unroll
            for (int e = 0; e < 4; ++e) acc[e] += lv * Ad[m * PAD2 + pc_ + 32 * e];
        }
        __syncthreads();
        #pragma unroll
        for (int e = 0; e < 4; ++e) Ad[i * PAD2 + pc_ + 32 * e] += s * acc[e];
        __syncthreads();
    }

    // ---- LU with partial pivoting, in place, fp64
    for (int k = 0; k < N - 1; ++k) {
        if (wid == 0) {
            float v0 = (l >= k) ? (float)fabs(Ad[l * PAD2 + k]) : -1.0f;
            float v1 = (rB >= k) ? (float)fabs(Ad[rB * PAD2 + k]) : -1.0f;
            float vm = v0; int im = l;
            if (v1 > vm) { vm = v1; im = rB; }
            #pragma unroll
            for (int o = 32; o > 0; o >>= 1) {
                float ov = __shfl_xor(vm, o);
                int   oi = __shfl_xor(im, o);
                if (ov > vm) { vm = ov; im = oi; }
            }
            if (l == 0) dinvd[k] = 1.0 / Ad[im * PAD2 + k];
            if (im != k) {
                double t0 = Ad[k * PAD2 + l];
                Ad[k * PAD2 + l] = Ad[im * PAD2 + l];
                Ad[im * PAD2 + l] = t0;
                double t1 = Ad[k * PAD2 + rB];
                Ad[k * PAD2 + rB] = Ad[im * PAD2 + rB];
                Ad[im * PAD2 + rB] = t1;
            }
        }
        __syncthreads();
        double invd = dinvd[k];
        int g32 = tid >> 5, l32 = tid & 31;
        double ukj[4];
        #pragma unroll
        for (int m2 = 0; m2 < 4; ++m2) {
            int j = k + 1 + l32 + 32 * m2;
            ukj[m2] = (j < N) ? Ad[k * PAD2 + j] : 0.0;
        }
        #pragma unroll 2
        for (int i = k + 1 + g32; i < N; i += 32) {
            double lik = Ad[i * PAD2 + k] * invd;
            if (l32 == 0) Ad[i * PAD2 + k] = lik;
            #pragma unroll
            for (int m2 = 0; m2 < 4; ++m2) {
                int j = k + 1 + l32 + 32 * m2;
                if (j < N) Ad[i * PAD2 + j] -= lik * ukj[m2];
            }
        }
        __syncthreads();
    }
    if (tid == 0) dinvd[N - 1] = 1.0 / Ad[(N - 1) * PAD2 + (N - 1)];
    __syncthreads();

    // ================= power iteration: all 16 waves, direct LDS reads =================
    {
        const int pr = tid >> 3;      // row 0..127
        const int pc = tid & 7;       // 8 lanes per row, strided elements
        if (tid < 128) {
            float4 xv;
            xv.x = hashf(13u + (unsigned)tid * 7919u);
            xv.y = hashf(14u + (unsigned)tid * 7919u);
            xv.z = hashf(15u + (unsigned)tid * 7919u);
            xv.w = hashf(16u + (unsigned)tid * 7919u);
            fX4[XI(tid)] = xv;
        }
        __syncthreads();

        float4* Xin = fX4;
        float4* Xout = fW4;
        const int wv = tid >> 6;      // 0/1 for tid<128

        for (int it = 0; it < POWER_IT; ++it) {
            sweep4<0>(Ad, Xin, Xout, pr, pc); __syncthreads();
            { float4* tmp = Xin; Xin = Xout; Xout = tmp; }
            sweep4<1>(Ad, Xin, Xout, pr, pc); __syncthreads();
            { float4* tmp = Xin; Xin = Xout; Xout = tmp; }
            sweep4<2>(Ad, Xin, Xout, pr, pc); __syncthreads();
            { float4* tmp = Xin; Xin = Xout; Xout = tmp; }
            sweep4<3>(Ad, Xin, Xout, pr, pc); __syncthreads();
            { float4* tmp = Xin; Xin = Xout; Xout = tmp; }

            if ((it & 1) == 0) {
                // cheap per-vector normalization
                if (tid < 128) {
                    float4 x = Xin[XI(tid)];
                    float n0 = x.x*x.x, n1 = x.y*x.y, n2 = x.z*x.z, n3 = x.w*x.w;
                    #pragma unroll
                    for (int o = 32; o > 0; o >>= 1) {
                        n0 += __shfl_xor(n0, o); n1 += __shfl_xor(n1, o);
                        n2 += __shfl_xor(n2, o); n3 += __shfl_xor(n3, o);
                    }
                    if (l == 0) {
                        dred[wv*4 + 0] = (double)n0; dred[wv*4 + 1] = (double)n1;
                        dred[wv*4 + 2] = (double)n2; dred[wv*4 + 3] = (double)n3;
                    }
                }
                __syncthreads();
                if (tid < 128) {
                    float i0 = rsqrtf((float)(dred[0] + dred[4]) + 1e-30f);
                    float i1 = rsqrtf((float)(dred[1] + dred[5]) + 1e-30f);
                    float i2 = rsqrtf((float)(dred[2] + dred[6]) + 1e-30f);
                    float i3 = rsqrtf((float)(dred[3] + dred[7]) + 1e-30f);
                    float4 x = Xin[XI(tid)];
                    x.x *= i0; x.y *= i1; x.z *= i2; x.w *= i3;
                    Xin[XI(tid)] = x;
                }
                __syncthreads();
            } else {
                // CholQR orthonormalization -- SPILL FIX (r11): the 128-thread path holds only
                // p[10] (during shfl reduce) then xs/xn; the 4x4 inverse (Gp[10]+C[16], the
                // round-6..10 spill source at the 64-VGPR cap) runs on tid0 ONLY, into LDS dG.
                if (tid < 128) {
                    float4 x = Xin[XI(tid)];
                    float xs[4] = {x.x, x.y, x.z, x.w};
                    double p[10];
                    { int c = 0;
                      #pragma unroll
                      for (int v = 0; v < 4; ++v)
                          #pragma unroll
                          for (int w2 = v; w2 < 4; ++w2) { p[c] = (double)xs[v] * xs[w2]; ++c; } }
                    #pragma unroll
                    for (int o = 32; o > 0; o >>= 1)
                        #pragma unroll
                        for (int c2 = 0; c2 < 10; ++c2) p[c2] += __shfl_xor(p[c2], o);
                    if (l == 0)
                        for (int c2 = 0; c2 < 10; ++c2) dred[wv*10 + c2] = p[c2];
                }
                __syncthreads();
                if (tid == 0) {
                    double Gp[10];
                    #pragma unroll
                    for (int c2 = 0; c2 < 10; ++c2) Gp[c2] = dred[c2] + dred[10 + c2];
                    cholInvC(Gp, dG);   // writes 16 doubles to LDS
                }
                __syncthreads();
                if (tid < 128) {
                    float4 x = Xin[XI(tid)];
                    double x0 = x.x, x1 = x.y, x2 = x.z, x3 = x.w;
                    float n0 = (float)(dG[0]*x0);
                    float n1 = (float)(dG[1]*x0 + dG[5]*x1);
                    float n2 = (float)(dG[2]*x0 + dG[6]*x1 + dG[10]*x2);
                    float n3 = (float)(dG[3]*x0 + dG[7]*x1 + dG[11]*x2 + dG[15]*x3);
                    Xin[XI(tid)] = make_float4(n0, n1, n2, n3);
                }
                __syncthreads();
            }
        }

        // Ritz for lambda_max: y = L U x (x orthonormal), Gram(y), jacobi
        sweep4<0>(Ad, Xin, Xout, pr, pc); __syncthreads();
        { float4* tmp = Xin; Xin = Xout; Xout = tmp; }
        sweep4<1>(Ad, Xin, Xout, pr, pc); __syncthreads();
        { float4* tmp = Xin; Xin = Xout; Xout = tmp; }
        if (tid < 128) {
            float4 x = Xin[XI(tid)];
            float xs[4] = {x.x, x.y, x.z, x.w};
            double p[10];
            { int c = 0;
              #pragma unroll
              for (int v = 0; v < 4; ++v)
                  #pragma unroll
                  for (int w2 = v; w2 < 4; ++w2) { p[c] = (double)xs[v] * xs[w2]; ++c; } }
            #pragma unroll
            for (int o = 32; o > 0; o >>= 1)
                #pragma unroll
                for (int c2 = 0; c2 < 10; ++c2) p[c2] += __shfl_xor(p[c2], o);
            if (l == 0)
                for (int c2 = 0; c2 < 10; ++c2) dred[wv*10 + c2] = p[c2];
        }
        __syncthreads();
        if (tid == 0) {
            double Gp[10];
            #pragma unroll
            for (int c2 = 0; c2 < 10; ++c2) Gp[c2] = dred[c2] + dred[10 + c2];
            dmisc[0] = jacobi4_lmax(Gp);
        }
        // no barrier needed: inverse phase below only reads Ad/dinvd (stable since LU)
    }

    // ================= inverse iteration: 16 independent block-2 fp64 chains =================
    {
        unsigned seed = 2654435761u * (unsigned)(wid + 1) + 12345u;
        double ya[2], yb[2];
        #pragma unroll
        for (int v = 0; v < 2; ++v) {
            ya[v] = (double)hashf(seed + (unsigned)(v * 337 + l * 101 + 7));
            yb[v] = (double)hashf(seed + (unsigned)(v * 337 + rB * 101 + 7));
        }
        for (int it = 0; it < INV_IT; ++it) {
            // (a) U^T a = y, forward
            #pragma unroll 4
            for (int i = 0; i < 64; ++i) {
                double invd = dinvd[i];
                double u0 = Ad[i * PAD2 + l];
                double u1 = Ad[i * PAD2 + rB];
                bool up0 = (l > i);
                #pragma unroll
                for (int v = 0; v < 2; ++v) {
                    double av = readlane_d(ya[v], i) * invd;
                    double upd = ya[v] - u0 * av;
                    ya[v] = (l == i) ? av : (up0 ? upd : ya[v]);
                    yb[v] -= u1 * av;
                }
            }
            #pragma unroll 4
            for (int i2 = 0; i2 < 64; ++i2) {
                double invd = dinvd[64 + i2];
                double u1 = Ad[(64 + i2) * PAD2 + rB];
                bool up1 = (l > i2);
                #pragma unroll
                for (int v = 0; v < 2; ++v) {
                    double av = readlane_d(yb[v], i2) * invd;
                    double upd = yb[v] - u1 * av;
                    yb[v] = (l == i2) ? av : (up1 ? upd : yb[v]);
                }
            }
            // (b) L^T b = a, backward (unit diag)
            #pragma unroll 4
            for (int j2 = 63; j2 >= 0; --j2) {
                int j = 64 + j2;
                double L0 = Ad[j * PAD2 + l];
                double L1 = Ad[j * PAD2 + rB];
                bool m1 = (l < j2);
                #pragma unroll
                for (int v = 0; v < 2; ++v) {
                    double bv = readlane_d(yb[v], j2);
                    ya[v] -= L0 * bv;
                    double upd = yb[v] - L1 * bv;
                    yb[v] = m1 ? upd : yb[v];
                }
            }
            #pragma unroll 4
            for (int j = 63; j >= 1; --j) {
                double L0 = Ad[j * PAD2 + l];
                bool m0 = (l < j);
                #pragma unroll
                for (int v = 0; v < 2; ++v) {
                    double bv = readlane_d(ya[v], j);
                    double upd = ya[v] - L0 * bv;
                    ya[v] = m0 ? upd : ya[v];
                }
            }
            // (c) L c = b, forward (unit diag)
            #pragma unroll 4
            for (int j = 0; j < 64; ++j) {
                double La0 = Ad[l * PAD2 + j];
                double La1 = Ad[rB * PAD2 + j];
                bool m0 = (l > j);
                #pragma unroll
                for (int v = 0; v < 2; ++v) {
                    double cv = readlane_d(ya[v], j);
                    double upd = ya[v] - La0 * cv;
                    ya[v] = m0 ? upd : ya[v];
                    yb[v] -= La1 * cv;
                }
            }
            #pragma unroll 4
            for (int j2 = 0; j2 < 64; ++j2) {
                double La1 = Ad[rB * PAD2 + 64 + j2];
                bool m1 = (l > j2);
                #pragma unroll
                for (int v = 0; v < 2; ++v) {
                    double cv = readlane_d(yb[v], j2);
                    double upd = yb[v] - La1 * cv;
                    yb[v] = m1 ? upd : yb[v];
                }
            }
            // (d) U x = c, backward
            #pragma unroll 4
            for (int i2 = 63; i2 >= 0; --i2) {
                int i = 64 + i2;
                double invd = dinvd[i];
                double U0 = Ad[l * PAD2 + i];
                double U1 = Ad[rB * PAD2 + i];
                bool m1 = (l < i2);
                #pragma unroll
                for (int v = 0; v < 2; ++v) {
                    double xv = readlane_d(yb[v], i2) * invd;
                    ya[v] -= U0 * xv;
                    double upd = yb[v] - U1 * xv;
                    yb[v] = (l == i2) ? xv : (m1 ? upd : yb[v]);
                }
            }
            #pragma unroll 4
            for (int i = 63; i >= 0; --i) {
                double invd = dinvd[i];
                double U0 = Ad[l * PAD2 + i];
                bool m0 = (l < i);
                #pragma unroll
                for (int v = 0; v < 2; ++v) {
                    double xv = readlane_d(ya[v], i) * invd;
                    double upd = ya[v] - U0 * xv;
                    ya[v] = (l == i) ? xv : (m0 ? upd : ya[v]);
                }
            }
            cholqr2_d(ya, yb);
            cholqr2_d(ya, yb);
        }
        // Ritz for lambda_min: z = L U y, 2x2 Gram
        double t0[2] = {0, 0}, t1[2] = {0, 0};
        #pragma unroll 4
        for (int j = 0; j < 64; ++j) {
            double u0 = Ad[l * PAD2 + j];
            u0 = (j >= l) ? u0 : 0.0;
            #pragma unroll
            for (int v = 0; v < 2; ++v) { double yj = readlane_d(ya[v], j); t0[v] += u0 * yj; }
        }
        #pragma unroll 4
        for (int j2 = 0; j2 < 64; ++j2) {
            int j = 64 + j2;
            double u0 = Ad[l * PAD2 + j];
            double u1 = Ad[rB * PAD2 + j];
            u1 = (j2 >= l) ? u1 : 0.0;
            #pragma unroll
            for (int v = 0; v < 2; ++v) {
                double yj = readlane_d(yb[v], j2);
                t0[v] += u0 * yj; t1[v] += u1 * yj;
            }
        }
        double z0[2] = {t0[0], t0[1]}, z1[2] = {t1[0], t1[1]};
        #pragma unroll 4
        for (int j = 0; j < 64; ++j) {
            double L0 = Ad[l * PAD2 + j];
            L0 = (j < l) ? L0 : 0.0;
            double L1 = Ad[rB * PAD2 + j];
            #pragma unroll
            for (int v = 0; v < 2; ++v) {
                double tj = readlane_d(t0[v], j);
                z0[v] += L0 * tj; z1[v] += L1 * tj;
            }
        }
        #pragma unroll 4
        for (int j2 = 0; j2 < 64; ++j2) {
            double L1 = Ad[rB * PAD2 + 64 + j2];
            L1 = (j2 < l) ? L1 : 0.0;
            #pragma unroll
            for (int v = 0; v < 2; ++v) {
                double tj = readlane_d(t1[v], j2);
                z1[v] += L1 * tj;
            }
        }
        double g00 = z0[0]*z0[0] + z1[0]*z1[0];
        double g01 = z0[0]*z0[1] + z1[0]*z1[1];
        double g11 = z0[1]*z0[1] + z1[1]*z1[1];
        #pragma unroll
        for (int o = 32; o > 0; o >>= 1) {
            g00 += __shfl_xor(g00, o);
            g01 += __shfl_xor(g01, o);
            g11 += __shfl_xor(g11, o);
        }
        double dif = g00 - g11;
        double lmin = 0.5 * ((g00 + g11) - sqrt(dif * dif + 4.0 * g01 * g01));
        if (l == 0) dmisc[1 + wid] = lmin;
    }
    __syncthreads();
    if (tid == 0) {
        double lmin = dmisc[1];
        #pragma unroll
        for (int w2 = 2; w2 <= 16; ++w2) lmin = fmin(lmin, dmisc[w2]);
        conds[b] = sqrt(fmax(dmisc[0], 0.0) / fmax(lmin, 1e-290));
    }
}

__global__ void reduce_kernel(const double* __restrict__ conds, float* __restrict__ out, int B) {
    __shared__ double sred[4];
    int tid = threadIdx.x;
    double acc = 0.0;
    for (int i = tid; i < B; i += 256) acc += conds[i];
    #pragma unroll
    for (int o = 32; o > 0; o >>= 1) acc += __shfl_xor(acc, o);
    if ((tid & 63) == 0) sred[tid >> 6] = acc;
    __syncthreads();
    if (tid == 0) out[0] = (float)((sred[0] + sred[1] + sred[2] + sred[3]) / (double)B);
}

extern "C" void kernel_launch(void* const* d_in, const int* in_sizes, int n_in,
                              void* d_out, int out_size, void* d_ws, size_t ws_size,
                              hipStream_t stream) {
    const float* DD = (const float*)d_in[0];
    const float* LE = (const float*)d_in[1];
    const float* SC = (const float*)d_in[2];
    float* out = (float*)d_out;
    int B = in_sizes[0] / (N * N);
    double* conds = (double*)d_ws;

    static_assert(SMEM_BYTES <= 160 * 1024, "LDS budget");
    (void)hipFuncSetAttribute((const void*)cond_kernel,
                              hipFuncAttributeMaxDynamicSharedMemorySize, (int)SMEM_BYTES);
    hipLaunchKernelGGL(cond_kernel, dim3(B), dim3(NTHREADS), SMEM_BYTES, stream, DD, LE, SC, conds);
    hipLaunchKernelGGL(reduce_kernel, dim3(1), dim3(256), 0, stream, conds, out, B);
}

// Round 12
// 4308.907 us; speedup vs baseline: 1.5530x; 1.5530x over previous
//
#include <hip/hip_runtime.h>

#define N 128
#define PAD2 129
#define NL 8128
#define POWER_IT 10   // even: last iteration ends with CholQR (orthonormal for Ritz)
#define INV_IT 3
#define INV_WAVES 8   // inverse chains on waves 0..7 only (2/SIMD): phase is issue-bound
#define NTHREADS 1024

// LDS layout (doubles first):
//   Ad[128*129] fp64 matrix (132096 B) -> L,U after LU
//   dinvd[128]  1/U[k,k]
//   dmisc[24]   [0]=lmax, [1..8]=lmin per inverse wave
//   dred[24]    reduction scratch (norm: 8, CholQR/Gram: 20)
//   dG[16]      4x4 R^{-1} (upper), tid0 -> LDS broadcast
// then float4 region (padded index XI): fX4[143], fW4[143]
#define NDBL (16512 + 128 + 24 + 24 + 16)     // 16704 doubles = 133632 B
#define SMEM_BYTES (NDBL * 8 + 2 * 143 * 16)  // 133632 + 4576 = 138208
#define XI(j) ((j) + ((j) >> 3))              // bank-skew pad for float4 vectors

static __device__ __forceinline__ float hashf(unsigned x) {
    x ^= 2747636419u; x *= 2654435769u; x ^= x >> 16;
    x *= 2654435769u; x ^= x >> 16; x *= 2654435769u;
    return ((float)(x >> 8)) * (1.0f / 16777216.0f) - 0.5f;
}
static __device__ __forceinline__ double readlane_d(double x, int lane) {
    int lo = __builtin_amdgcn_readlane(__double2loint(x), lane);
    int hi = __builtin_amdgcn_readlane(__double2hiint(x), lane);
    return __hiloint2double(hi, lo);
}

// Cholesky of 4x4 Gram (packed upper, 10) -> C = R^{-1} (upper, row-major 4x4).
// Called by tid0 ONLY; C points to LDS.
static __device__ __forceinline__ void cholInvC(const double* Gp, double* C) {
    double g[4][4];
    int c = 0;
    #pragma unroll
    for (int a = 0; a < 4; ++a)
        #pragma unroll
        for (int b2 = a; b2 < 4; ++b2) { g[a][b2] = Gp[c]; g[b2][a] = Gp[c]; ++c; }
    double R[4][4];
    #pragma unroll
    for (int i = 0; i < 4; ++i) {
        double d = g[i][i];
        #pragma unroll
        for (int m = 0; m < 4; ++m) if (m < i) d -= R[m][i] * R[m][i];
        d = sqrt(fmax(d, 1e-300));
        R[i][i] = d;
        #pragma unroll
        for (int j = 0; j < 4; ++j) if (j > i) {
            double v = g[i][j];
            #pragma unroll
            for (int m = 0; m < 4; ++m) if (m < i) v -= R[m][i] * R[m][j];
            R[i][j] = v / d;
        }
    }
    #pragma unroll
    for (int j = 3; j >= 0; --j) {
        C[j*4 + j] = 1.0 / R[j][j];
        #pragma unroll
        for (int i = 3; i >= 0; --i) if (i < j) {
            double v = 0.0;
            #pragma unroll
            for (int m = 0; m < 4; ++m) if (m > i && m <= j) v += R[i][m] * C[m*4 + j];
            C[i*4 + j] = -v / R[i][i];
        }
        #pragma unroll
        for (int i = 0; i < 4; ++i) if (i > j) C[i*4 + j] = 0.0;
    }
}

static __device__ __forceinline__ double jacobi4_lmax(const double* Gp) {
    double g[4][4];
    int c = 0;
    #pragma unroll
    for (int a = 0; a < 4; ++a)
        #pragma unroll
        for (int b2 = a; b2 < 4; ++b2) { g[a][b2] = Gp[c]; g[b2][a] = Gp[c]; ++c; }
    #pragma unroll
    for (int sweep = 0; sweep < 6; ++sweep) {
        #pragma unroll
        for (int p = 0; p < 3; ++p) {
            #pragma unroll
            for (int q = p + 1; q < 4; ++q) {
                double apq = g[p][q];
                double tau = (g[q][q] - g[p][p]) / (2.0 * apq);
                double t = (tau >= 0.0 ? 1.0 : -1.0) / (fabs(tau) + sqrt(1.0 + tau * tau));
                if (fabs(apq) < 1e-280) t = 0.0;
                double cc = 1.0 / sqrt(1.0 + t * t);
                double ss = t * cc;
                #pragma unroll
                for (int r = 0; r < 4; ++r) {
                    double grp = g[r][p], grq = g[r][q];
                    g[r][p] = cc * grp - ss * grq;
                    g[r][q] = ss * grp + cc * grq;
                }
                #pragma unroll
                for (int r = 0; r < 4; ++r) {
                    double gpr = g[p][r], gqr = g[q][r];
                    g[p][r] = cc * gpr - ss * gqr;
                    g[q][r] = ss * gpr + cc * gqr;
                }
            }
        }
    }
    return fmax(fmax(g[0][0], g[1][1]), fmax(g[2][2], g[3][3]));
}

static __device__ __forceinline__ void cholqr2_d(double ya[2], double yb[2]) {
    double g00 = ya[0]*ya[0] + yb[0]*yb[0];
    double g01 = ya[0]*ya[1] + yb[0]*yb[1];
    double g11 = ya[1]*ya[1] + yb[1]*yb[1];
    #pragma unroll
    for (int o = 32; o > 0; o >>= 1) {
        g00 += __shfl_xor(g00, o);
        g01 += __shfl_xor(g01, o);
        g11 += __shfl_xor(g11, o);
    }
    double r00 = sqrt(fmax(g00, 1e-300));
    double r01 = g01 / r00;
    double r11 = sqrt(fmax(g11 - r01 * r01, fabs(g11) * 1e-26 + 1e-300));
    double c00 = 1.0 / r00, c11 = 1.0 / r11;
    double c01 = -r01 * c00 * c11;
    double a0 = ya[0]*c00,             b0 = yb[0]*c00;
    double a1 = ya[0]*c01 + ya[1]*c11, b1 = yb[0]*c01 + yb[1]*c11;
    ya[0] = a0; yb[0] = b0; ya[1] = a1; yb[1] = b1;
}

// One triangular sweep of the block-4 power iteration, all 16 waves.
// Row pr = tid>>3 (0..127); lane pc = tid&7 handles elements j = pc + 8t.
// Direct LDS reads: NO per-thread arrays (rule #20 / round-4+5 spill lesson).
// MODE 0: out = U  * in            (row, j >= pr)
// MODE 1: out = L  * in, unit diag (row, j <  pr, + in[pr])
// MODE 2: out = L^T* in, unit diag (col, j >  pr, + in[pr])
// MODE 3: out = U^T* in            (col, j <= pr)
template<int MODE>
static __device__ __forceinline__ void sweep4(const double* __restrict__ Ad,
                                              const float4* __restrict__ Xin,
                                              float4* __restrict__ Xout,
                                              int pr, int pc) {
    float a0 = 0.f, a1 = 0.f, a2 = 0.f, a3 = 0.f;
    #pragma unroll
    for (int t = 0; t < 16; ++t) {
        int j = pc + (t << 3);
        float a = (MODE < 2) ? (float)Ad[pr * PAD2 + j] : (float)Ad[j * PAD2 + pr];
        bool keep = (MODE == 0) ? (j >= pr) : (MODE == 1) ? (j < pr)
                  : (MODE == 2) ? (j > pr)  : (j <= pr);
        a = keep ? a : 0.f;
        float4 xv = Xin[XI(j)];
        a0 += a * xv.x; a1 += a * xv.y; a2 += a * xv.z; a3 += a * xv.w;
    }
    a0 += __shfl_xor(a0, 1); a0 += __shfl_xor(a0, 2); a0 += __shfl_xor(a0, 4);
    a1 += __shfl_xor(a1, 1); a1 += __shfl_xor(a1, 2); a1 += __shfl_xor(a1, 4);
    a2 += __shfl_xor(a2, 1); a2 += __shfl_xor(a2, 2); a2 += __shfl_xor(a2, 4);
    a3 += __shfl_xor(a3, 1); a3 += __shfl_xor(a3, 2); a3 += __shfl_xor(a3, 4);
    if (pc == 0) {
        float4 o = make_float4(a0, a1, a2, a3);
        if (MODE == 1 || MODE == 2) {
            float4 iv = Xin[XI(pr)];
            o.x += iv.x; o.y += iv.y; o.z += iv.z; o.w += iv.w;
        }
        Xout[XI(pr)] = o;
    }
}

__global__ __launch_bounds__(NTHREADS)
__attribute__((amdgpu_waves_per_eu(4, 4)))
void cond_kernel(const float* __restrict__ DD, const float* __restrict__ LE,
                 const float* __restrict__ SCL, double* __restrict__ conds)
{
    extern __shared__ char smraw[];
    double* Ad    = (double*)smraw;        // 16512
    double* dinvd = Ad + N * PAD2;         // 128
    double* dmisc = dinvd + 128;           // 24
    double* dred  = dmisc + 24;            // 24
    double* dG    = dred + 24;             // 16
    float4* fX4   = (float4*)(Ad + NDBL);  // 143
    float4* fW4   = fX4 + 143;             // 143

    const int tid = threadIdx.x;
    const int b   = blockIdx.x;
    const int wid = tid >> 6;
    const int l   = tid & 63;
    const int rB  = l + 64;
    const double s = (double)SCL[0];
    const float* dd = DD + (size_t)b * (N * N);
    const float* le = LE + (size_t)b * NL;

    // ---- stage DD -> fp64
    for (int t = tid; t < (N * N) / 4; t += NTHREADS) {
        float4 dv = reinterpret_cast<const float4*>(dd)[t];
        int elem = t * 4;
        int i = elem >> 7, j = elem & 127;
        double* dst = &Ad[i * PAD2 + j];
        dst[0] = (double)dv.x; dst[1] = (double)dv.y;
        dst[2] = (double)dv.z; dst[3] = (double)dv.w;
    }
    __syncthreads();

    const int pr_ = tid >> 5;   // 0..31: row in 32-row block
    const int pc_ = tid & 31;   // col group: cols pc_+32e, e<4

    // ---- Pass A: T = D + s * E^T D (E = strict-lower le), ascending 32-row blocks
    for (int KB = 0; KB < N; KB += 32) {
        const int k = KB + pr_;
        double acc[4];
        #pragma unroll
        for (int e = 0; e < 4; ++e) acc[e] = 0.0;
        int off = (KB + 1) * KB / 2 + k;
        #pragma unroll 4
        for (int i = KB + 1; i < N; ++i) {
            int offs = (i > k) ? off : 0;
            float lef = le[offs];
            double lv = (i > k) ? (double)lef : 0.0;
            #pragma unroll
            for (int e = 0; e < 4; ++e) acc[e] += lv * Ad[i * PAD2 + pc_ + 32 * e];
            off += i;
        }
        __syncthreads();
        #pragma unroll
        for (int e = 0; e < 4; ++e) Ad[k * PAD2 + pc_ + 32 * e] += s * acc[e];
        __syncthreads();
    }

    // ---- Pass B: P = T + s * E T, descending 32-row blocks
    for (int IB = N - 32; IB >= 0; IB -= 32) {
        const int i = IB + pr_;
        const float* er = le + i * (i - 1) / 2;
        double acc[4];
        #pragma unroll
        for (int e = 0; e < 4; ++e) acc[e] = 0.0;
        #pragma unroll 4
        for (int m = 0; m < IB + 32; ++m) {
            int mm = (m < i) ? m : 0;
            float lef = er[mm];
            double lv = (m < i) ? (double)lef : 0.0;
            #pragma unroll
            for (int e = 0; e < 4; ++e) acc[e] += lv * Ad[m * PAD2 + pc_ + 32 * e];
        }
        __syncthreads();
        #pragma unroll
        for (int e = 0; e < 4; ++e) Ad[i * PAD2 + pc_ + 32 * e] += s * acc[e];
        __syncthreads();
    }

    // ---- LU with partial pivoting, in place, fp64
    for (int k = 0; k < N - 1; ++k) {
        if (wid == 0) {
            float v0 = (l >= k) ? (float)fabs(Ad[l * PAD2 + k]) : -1.0f;
            float v1 = (rB >= k) ? (float)fabs(Ad[rB * PAD2 + k]) : -1.0f;
            float vm = v0; int im = l;
            if (v1 > vm) { vm = v1; im = rB; }
            #pragma unroll
            for (int o = 32; o > 0; o >>= 1) {
                float ov = __shfl_xor(vm, o);
                int   oi = __shfl_xor(im, o);
                if (ov > vm) { vm = ov; im = oi; }
            }
            if (l == 0) dinvd[k] = 1.0 / Ad[im * PAD2 + k];
            if (im != k) {
                double t0 = Ad[k * PAD2 + l];
                Ad[k * PAD2 + l] = Ad[im * PAD2 + l];
                Ad[im * PAD2 + l] = t0;
                double t1 = Ad[k * PAD2 + rB];
                Ad[k * PAD2 + rB] = Ad[im * PAD2 + rB];
                Ad[im * PAD2 + rB] = t1;
            }
        }
        __syncthreads();
        double invd = dinvd[k];
        int g32 = tid >> 5, l32 = tid & 31;
        double ukj[4];
        #pragma unroll
        for (int m2 = 0; m2 < 4; ++m2) {
            int j = k + 1 + l32 + 32 * m2;
            ukj[m2] = (j < N) ? Ad[k * PAD2 + j] : 0.0;
        }
        #pragma unroll 2
        for (int i = k + 1 + g32; i < N; i += 32) {
            double lik = Ad[i * PAD2 + k] * invd;
            if (l32 == 0) Ad[i * PAD2 + k] = lik;
            #pragma unroll
            for (int m2 = 0; m2 < 4; ++m2) {
                int j = k + 1 + l32 + 32 * m2;
                if (j < N) Ad[i * PAD2 + j] -= lik * ukj[m2];
            }
        }
        __syncthreads();
    }
    if (tid == 0) dinvd[N - 1] = 1.0 / Ad[(N - 1) * PAD2 + (N - 1)];
    __syncthreads();

    // ================= power iteration: all 16 waves, direct LDS reads =================
    {
        const int pr = tid >> 3;      // row 0..127
        const int pc = tid & 7;       // 8 lanes per row, strided elements
        if (tid < 128) {
            float4 xv;
            xv.x = hashf(13u + (unsigned)tid * 7919u);
            xv.y = hashf(14u + (unsigned)tid * 7919u);
            xv.z = hashf(15u + (unsigned)tid * 7919u);
            xv.w = hashf(16u + (unsigned)tid * 7919u);
            fX4[XI(tid)] = xv;
        }
        __syncthreads();

        float4* Xin = fX4;
        float4* Xout = fW4;
        const int wv = tid >> 6;      // 0/1 for tid<128

        for (int it = 0; it < POWER_IT; ++it) {
            sweep4<0>(Ad, Xin, Xout, pr, pc); __syncthreads();
            { float4* tmp = Xin; Xin = Xout; Xout = tmp; }
            sweep4<1>(Ad, Xin, Xout, pr, pc); __syncthreads();
            { float4* tmp = Xin; Xin = Xout; Xout = tmp; }
            sweep4<2>(Ad, Xin, Xout, pr, pc); __syncthreads();
            { float4* tmp = Xin; Xin = Xout; Xout = tmp; }
            sweep4<3>(Ad, Xin, Xout, pr, pc); __syncthreads();
            { float4* tmp = Xin; Xin = Xout; Xout = tmp; }

            if ((it & 1) == 0) {
                // cheap per-vector normalization
                if (tid < 128) {
                    float4 x = Xin[XI(tid)];
                    float n0 = x.x*x.x, n1 = x.y*x.y, n2 = x.z*x.z, n3 = x.w*x.w;
                    #pragma unroll
                    for (int o = 32; o > 0; o >>= 1) {
                        n0 += __shfl_xor(n0, o); n1 += __shfl_xor(n1, o);
                        n2 += __shfl_xor(n2, o); n3 += __shfl_xor(n3, o);
                    }
                    if (l == 0) {
                        dred[wv*4 + 0] = (double)n0; dred[wv*4 + 1] = (double)n1;
                        dred[wv*4 + 2] = (double)n2; dred[wv*4 + 3] = (double)n3;
                    }
                }
                __syncthreads();
                if (tid < 128) {
                    float i0 = rsqrtf((float)(dred[0] + dred[4]) + 1e-30f);
                    float i1 = rsqrtf((float)(dred[1] + dred[5]) + 1e-30f);
                    float i2 = rsqrtf((float)(dred[2] + dred[6]) + 1e-30f);
                    float i3 = rsqrtf((float)(dred[3] + dred[7]) + 1e-30f);
                    float4 x = Xin[XI(tid)];
                    x.x *= i0; x.y *= i1; x.z *= i2; x.w *= i3;
                    Xin[XI(tid)] = x;
                }
                __syncthreads();
            } else {
                // CholQR orthonormalization (Gram via shfl, 4x4 inverse on tid0 -> LDS dG)
                if (tid < 128) {
                    float4 x = Xin[XI(tid)];
                    float xs[4] = {x.x, x.y, x.z, x.w};
                    double p[10];
                    { int c = 0;
                      #pragma unroll
                      for (int v = 0; v < 4; ++v)
                          #pragma unroll
                          for (int w2 = v; w2 < 4; ++w2) { p[c] = (double)xs[v] * xs[w2]; ++c; } }
                    #pragma unroll
                    for (int o = 32; o > 0; o >>= 1)
                        #pragma unroll
                        for (int c2 = 0; c2 < 10; ++c2) p[c2] += __shfl_xor(p[c2], o);
                    if (l == 0)
                        for (int c2 = 0; c2 < 10; ++c2) dred[wv*10 + c2] = p[c2];
                }
                __syncthreads();
                if (tid == 0) {
                    double Gp[10];
                    #pragma unroll
                    for (int c2 = 0; c2 < 10; ++c2) Gp[c2] = dred[c2] + dred[10 + c2];
                    cholInvC(Gp, dG);   // writes 16 doubles to LDS
                }
                __syncthreads();
                if (tid < 128) {
                    float4 x = Xin[XI(tid)];
                    double x0 = x.x, x1 = x.y, x2 = x.z, x3 = x.w;
                    float n0 = (float)(dG[0]*x0);
                    float n1 = (float)(dG[1]*x0 + dG[5]*x1);
                    float n2 = (float)(dG[2]*x0 + dG[6]*x1 + dG[10]*x2);
                    float n3 = (float)(dG[3]*x0 + dG[7]*x1 + dG[11]*x2 + dG[15]*x3);
                    Xin[XI(tid)] = make_float4(n0, n1, n2, n3);
                }
                __syncthreads();
            }
        }

        // Ritz for lambda_max: y = L U x (x orthonormal), Gram(y), jacobi
        sweep4<0>(Ad, Xin, Xout, pr, pc); __syncthreads();
        { float4* tmp = Xin; Xin = Xout; Xout = tmp; }
        sweep4<1>(Ad, Xin, Xout, pr, pc); __syncthreads();
        { float4* tmp = Xin; Xin = Xout; Xout = tmp; }
        if (tid < 128) {
            float4 x = Xin[XI(tid)];
            float xs[4] = {x.x, x.y, x.z, x.w};
            double p[10];
            { int c = 0;
              #pragma unroll
              for (int v = 0; v < 4; ++v)
                  #pragma unroll
                  for (int w2 = v; w2 < 4; ++w2) { p[c] = (double)xs[v] * xs[w2]; ++c; } }
            #pragma unroll
            for (int o = 32; o > 0; o >>= 1)
                #pragma unroll
                for (int c2 = 0; c2 < 10; ++c2) p[c2] += __shfl_xor(p[c2], o);
            if (l == 0)
                for (int c2 = 0; c2 < 10; ++c2) dred[wv*10 + c2] = p[c2];
        }
        __syncthreads();
        if (tid == 0) {
            double Gp[10];
            #pragma unroll
            for (int c2 = 0; c2 < 10; ++c2) Gp[c2] = dred[c2] + dred[10 + c2];
            dmisc[0] = jacobi4_lmax(Gp);
        }
        // no barrier needed: inverse phase below only reads Ad/dinvd (stable since LU)
    }

    // ====== inverse iteration: INV_WAVES independent block-2 fp64 chains (waves 0..7) ======
    // Phase is VALU-issue-bound; 2 active waves/SIMD instead of 4 halves its wall time.
    if (wid < INV_WAVES) {
        unsigned seed = 2654435761u * (unsigned)(wid + 1) + 12345u;
        double ya[2], yb[2];
        #pragma unroll
        for (int v = 0; v < 2; ++v) {
            ya[v] = (double)hashf(seed + (unsigned)(v * 337 + l * 101 + 7));
            yb[v] = (double)hashf(seed + (unsigned)(v * 337 + rB * 101 + 7));
        }
        for (int it = 0; it < INV_IT; ++it) {
            // (a) U^T a = y, forward
            #pragma unroll 4
            for (int i = 0; i < 64; ++i) {
                double invd = dinvd[i];
                double u0 = Ad[i * PAD2 + l];
                double u1 = Ad[i * PAD2 + rB];
                bool up0 = (l > i);
                #pragma unroll
                for (int v = 0; v < 2; ++v) {
                    double av = readlane_d(ya[v], i) * invd;
                    double upd = ya[v] - u0 * av;
                    ya[v] = (l == i) ? av : (up0 ? upd : ya[v]);
                    yb[v] -= u1 * av;
                }
            }
            #pragma unroll 4
            for (int i2 = 0; i2 < 64; ++i2) {
                double invd = dinvd[64 + i2];
                double u1 = Ad[(64 + i2) * PAD2 + rB];
                bool up1 = (l > i2);
                #pragma unroll
                for (int v = 0; v < 2; ++v) {
                    double av = readlane_d(yb[v], i2) * invd;
                    double upd = yb[v] - u1 * av;
                    yb[v] = (l == i2) ? av : (up1 ? upd : yb[v]);
                }
            }
            // (b) L^T b = a, backward (unit diag)
            #pragma unroll 4
            for (int j2 = 63; j2 >= 0; --j2) {
                int j = 64 + j2;
                double L0 = Ad[j * PAD2 + l];
                double L1 = Ad[j * PAD2 + rB];
                bool m1 = (l < j2);
                #pragma unroll
                for (int v = 0; v < 2; ++v) {
                    double bv = readlane_d(yb[v], j2);
                    ya[v] -= L0 * bv;
                    double upd = yb[v] - L1 * bv;
                    yb[v] = m1 ? upd : yb[v];
                }
            }
            #pragma unroll 4
            for (int j = 63; j >= 1; --j) {
                double L0 = Ad[j * PAD2 + l];
                bool m0 = (l < j);
                #pragma unroll
                for (int v = 0; v < 2; ++v) {
                    double bv = readlane_d(ya[v], j);
                    double upd = ya[v] - L0 * bv;
                    ya[v] = m0 ? upd : ya[v];
                }
            }
            // (c) L c = b, forward (unit diag)
            #pragma unroll 4
            for (int j = 0; j < 64; ++j) {
                double La0 = Ad[l * PAD2 + j];
                double La1 = Ad[rB * PAD2 + j];
                bool m0 = (l > j);
                #pragma unroll
                for (int v = 0; v < 2; ++v) {
                    double cv = readlane_d(ya[v], j);
                    double upd = ya[v] - La0 * cv;
                    ya[v] = m0 ? upd : ya[v];
                    yb[v] -= La1 * cv;
                }
            }
            #pragma unroll 4
            for (int j2 = 0; j2 < 64; ++j2) {
                double La1 = Ad[rB * PAD2 + 64 + j2];
                bool m1 = (l > j2);
                #pragma unroll
                for (int v = 0; v < 2; ++v) {
                    double cv = readlane_d(yb[v], j2);
                    double upd = yb[v] - La1 * cv;
                    yb[v] = m1 ? upd : yb[v];
                }
            }
            // (d) U x = c, backward
            #pragma unroll 4
            for (int i2 = 63; i2 >= 0; --i2) {
                int i = 64 + i2;
                double invd = dinvd[i];
                double U0 = Ad[l * PAD2 + i];
                double U1 = Ad[rB * PAD2 + i];
                bool m1 = (l < i2);
                #pragma unroll
                for (int v = 0; v < 2; ++v) {
                    double xv = readlane_d(yb[v], i2) * invd;
                    ya[v] -= U0 * xv;
                    double upd = yb[v] - U1 * xv;
                    yb[v] = (l == i2) ? xv : (m1 ? upd : yb[v]);
                }
            }
            #pragma unroll 4
            for (int i = 63; i >= 0; --i) {
                double invd = dinvd[i];
                double U0 = Ad[l * PAD2 + i];
                bool m0 = (l < i);
                #pragma unroll
                for (int v = 0; v < 2; ++v) {
                    double xv = readlane_d(ya[v], i) * invd;
                    double upd = ya[v] - U0 * xv;
                    ya[v] = (l == i) ? xv : (m0 ? upd : ya[v]);
                }
            }
            cholqr2_d(ya, yb);   // single fp64 CholQR suffices per iteration
        }
        // Ritz for lambda_min: z = L U y, 2x2 Gram
        double t0[2] = {0, 0}, t1[2] = {0, 0};
        #pragma unroll 4
        for (int j = 0; j < 64; ++j) {
            double u0 = Ad[l * PAD2 + j];
            u0 = (j >= l) ? u0 : 0.0;
            #pragma unroll
            for (int v = 0; v < 2; ++v) { double yj = readlane_d(ya[v], j); t0[v] += u0 * yj; }
        }
        #pragma unroll 4
        for (int j2 = 0; j2 < 64; ++j2) {
            int j = 64 + j2;
            double u0 = Ad[l * PAD2 + j];
            double u1 = Ad[rB * PAD2 + j];
            u1 = (j2 >= l) ? u1 : 0.0;
            #pragma unroll
            for (int v = 0; v < 2; ++v) {
                double yj = readlane_d(yb[v], j2);
                t0[v] += u0 * yj; t1[v] += u1 * yj;
            }
        }
        double z0[2] = {t0[0], t0[1]}, z1[2] = {t1[0], t1[1]};
        #pragma unroll 4
        for (int j = 0; j < 64; ++j) {
            double L0 = Ad[l * PAD2 + j];
            L0 = (j < l) ? L0 : 0.0;
            double L1 = Ad[rB * PAD2 + j];
            #pragma unroll
            for (int v = 0; v < 2; ++v) {
                double tj = readlane_d(t0[v], j);
                z0[v] += L0 * tj; z1[v] += L1 * tj;
            }
        }
        #pragma unroll 4
        for (int j2 = 0; j2 < 64; ++j2) {
            double L1 = Ad[rB * PAD2 + 64 + j2];
            L1 = (j2 < l) ? L1 : 0.0;
            #pragma unroll
            for (int v = 0; v < 2; ++v) {
                double tj = readlane_d(t1[v], j2);
                z1[v] += L1 * tj;
            }
        }
        double g00 = z0[0]*z0[0] + z1[0]*z1[0];
        double g01 = z0[0]*z0[1] + z1[0]*z1[1];
        double g11 = z0[1]*z0[1] + z1[1]*z1[1];
        #pragma unroll
        for (int o = 32; o > 0; o >>= 1) {
            g00 += __shfl_xor(g00, o);
            g01 += __shfl_xor(g01, o);
            g11 += __shfl_xor(g11, o);
        }
        double dif = g00 - g11;
        double lmin = 0.5 * ((g00 + g11) - sqrt(dif * dif + 4.0 * g01 * g01));
        if (l == 0) dmisc[1 + wid] = lmin;
    }
    __syncthreads();
    if (tid == 0) {
        double lmin = dmisc[1];
        #pragma unroll
        for (int w2 = 2; w2 <= INV_WAVES; ++w2) lmin = fmin(lmin, dmisc[w2]);
        conds[b] = sqrt(fmax(dmisc[0], 0.0) / fmax(lmin, 1e-290));
    }
}

__global__ void reduce_kernel(const double* __restrict__ conds, float* __restrict__ out, int B) {
    __shared__ double sred[4];
    int tid = threadIdx.x;
    double acc = 0.0;
    for (int i = tid; i < B; i += 256) acc += conds[i];
    #pragma unroll
    for (int o = 32; o > 0; o >>= 1) acc += __shfl_xor(acc, o);
    if ((tid & 63) == 0) sred[tid >> 6] = acc;
    __syncthreads();
    if (tid == 0) out[0] = (float)((sred[0] + sred[1] + sred[2] + sred[3]) / (double)B);
}

extern "C" void kernel_launch(void* const* d_in, const int* in_sizes, int n_in,
                              void* d_out, int out_size, void* d_ws, size_t ws_size,
                              hipStream_t stream) {
    const float* DD = (const float*)d_in[0];
    const float* LE = (const float*)d_in[1];
    const float* SC = (const float*)d_in[2];
    float* out = (float*)d_out;
    int B = in_sizes[0] / (N * N);
    double* conds = (double*)d_ws;

    static_assert(SMEM_BYTES <= 160 * 1024, "LDS budget");
    (void)hipFuncSetAttribute((const void*)cond_kernel,
                              hipFuncAttributeMaxDynamicSharedMemorySize, (int)SMEM_BYTES);
    hipLaunchKernelGGL(cond_kernel, dim3(B), dim3(NTHREADS), SMEM_BYTES, stream, DD, LE, SC, conds);
    hipLaunchKernelGGL(reduce_kernel, dim3(1), dim3(256), 0, stream, conds, out, B);
}